// Round 1
// 193.164 us; speedup vs baseline: 1.0544x; 1.0544x over previous
//
#include <hip/hip_runtime.h>
#include <hip/hip_bf16.h>
#include <math.h>

// PillarHist: per-row 64-bin hist (count/mean_z/mean_r interleaved) -> Linear(192->64) -> BN(train) -> ReLU
// k0 (16 blocks): build permuted bf16 B-fragments into d_ws + zero BN totals (16 replicas).
// k1 (3125 blocks, 32 rows/block): PAIR-SHARED hist for 2x occupancy.
//     Each 16-row hist strip (16 rows x 128 ints, rotation-swizzled bins) is shared by a PAIR of
//     waves: each wave loads+hists 8 rows (8 uint2 loads, 16 ds_add_u32), one __syncthreads,
//     then both waves MFMA the full 16-row A split by output half (t in {2j,2j+1}, 12 MFMAs).
//     LDS = 16 KB/block -> 8 blocks/CU -> 32 waves/CU (vs 16 before). VGPR capped at 64 via
//     __launch_bounds__(256,8). Packed fixed-point hist words as before:
//     z-word = count<<24 | biased z-payload ; r-word = biased r-payload.
//     Bin rotation swizzle (bi + 4*row) & 63 replaces the +4-int row pad (keeps the 2-way bank
//     profile of the col*128-strided A-reads while making rows exactly 512 B).
// k3: sum replicas -> scale/shift -> apply BN+ReLU in-place (grid-stride).

typedef __attribute__((ext_vector_type(8))) short bf16x8;   // 8 bf16 = 4 VGPRs = 16 B
typedef __attribute__((ext_vector_type(4))) float f32x4;
typedef __attribute__((ext_vector_type(4))) int   i32x4;

#define ZMINF   (-3.0f)
#define INV_BIN 16.0f            // 1/BIN_SIZE (exact pow2)
#define QS      8192.0f          // 2^13 payload scale
#define INV_QS  (1.0f / 8192.0f)
#define PBIASF  65536.0f         // 2^16 payload bias (covers |z|<8; 64*max_payload < 2^24)
#define PBIASI  65536
#define CBIT    16777216         // 2^24 count increment (z-word only)
#define TSC     16777216.0f      // 2^24 fixed-point scale for BN totals
#define INV_TSC (1.0f / 16777216.0f)
#define REPS    16               // BN total replicas

__device__ __forceinline__ short f2bf(float f) {
    __hip_bfloat16 h = __float2bfloat16(f);   // RNE
    return __builtin_bit_cast(short, h);
}

// ---- k0: grid-stride. Permuted W -> bf16 fragments (frag-major [s*4+t][lane][j]) + zero totals ----
__global__ __launch_bounds__(256)
void k0_prep(const float* __restrict__ W,                  // [64,192]
             short*       __restrict__ wsW,                // [24*64*8] bf16
             unsigned long long* __restrict__ totals)      // [REPS*128]
{
    const int tid    = blockIdx.x * 256 + threadIdx.x;
    const int stride = gridDim.x * 256;
    for (int e = tid; e < 24 * 64 * 8; e += stride) {
        const int j  = e & 7;
        const int ln = (e >> 3) & 63;
        const int st = e >> 9;                       // s*4+t
        const int s  = st >> 2, t = st & 3;
        const int k  = s * 32 + (ln >> 4) * 8 + j;   // planar k
        const int n  = t * 16 + (ln & 15);           // output channel
        const int wc = (k < 64) ? 3 * k
                     : (k < 128) ? 3 * (k - 64) + 1
                                 : 3 * (k - 128) + 2;
        wsW[e] = f2bf(W[n * 192 + wc]);
    }
    for (int e = tid; e < REPS * 128; e += stride) totals[e] = 0ull;
}

__global__ __launch_bounds__(256, 8)
void k1_hist_mfma(const uint2*  __restrict__ feat2,  // feat as uint2; zw of (row,pt) at (row*64+pt)*2+1
                  const int*    __restrict__ nump,   // [M]
                  const bf16x8* __restrict__ wsWf,   // [24*64] B fragments (global, L2-hot)
                  const float*  __restrict__ bvec,   // [64]
                  float*        __restrict__ xout,   // [M,64] pre-BN x (d_out)
                  unsigned long long* __restrict__ totals, // [REPS*128] fixed-point sum | sumsq
                  int M)
{
    __shared__ int sH[2 * 16 * 128];   // 16384 B: 2 pair-regions x 16 rows x (z[64]|r[64])

    const int tid  = threadIdx.x;
    const int wave = tid >> 6;
    const int lane = tid & 63;
    const int col  = lane & 15;
    const int quad = lane >> 4;
    const int pair = wave >> 1;
    const int half = wave & 1;          // output half: t in {2*half, 2*half+1}

    const int gbase = blockIdx.x * 32 + pair * 16;   // this pair's 16 rows
    int* hp = &sH[pair * 2048];

    float psum[2] = {0.f, 0.f};
    float psq[2]  = {0.f, 0.f};
    bf16x8 bcur[2];

    if (gbase < M) {
        // ---- 8 rows of z/w per wave in ONE load batch (uint2 = 8 B/lane; 16 VGPRs) ----
        uint2 zw[8];
        const int npv = nump[min(gbase + half * 8 + (lane & 7), M - 1)];  // lanes 0..7 hold own rows
        #pragma unroll
        for (int uu = 0; uu < 8; ++uu) {
            const int rc = min(gbase + half * 8 + uu, M - 1);
            zw[uu] = feat2[((size_t)rc * 64 + lane) * 2 + 1];
        }

        // ---- zero OWN 8-row strip (1024 ints); wave-private -> no barrier needed before hist ----
        {
            i32x4* p4 = (i32x4*)(hp + half * 1024);
            #pragma unroll
            for (int i = 0; i < 4; ++i) p4[lane + i * 64] = i32x4{0, 0, 0, 0};
        }
        __builtin_amdgcn_wave_barrier();

        // ---- packed hist, own 8 rows: 2 native ds_add_u32 per point, rotated bin slot ----
        #pragma unroll
        for (int uu = 0; uu < 8; ++uu) {
            const int u = half * 8 + uu;                         // row within pair region
            int np_u = __builtin_amdgcn_readlane(npv, uu);
            np_u = (gbase + u < M) ? np_u : 0;                   // uniform tail guard
            if (lane < np_u) {
                const float z  = __int_as_float((int)zw[uu].x);
                const float rr = __int_as_float((int)zw[uu].y);
                int bi = (int)((z - ZMINF) * INV_BIN);           // trunc, matches astype(int32)
                bi = min(max(bi, 0), 63);
                const int sw = (bi + u * 4) & 63;                // rotation swizzle
                int* hrow = hp + u * 128;
                atomicAdd(hrow + sw,      CBIT + PBIASI + (int)(z * QS));   // count | biased z
                atomicAdd(hrow + 64 + sw, PBIASI + (int)(rr * QS));         // biased r
            }
        }

        // ---- prefetch s=0 B-frags (L2-hot) so they complete by the barrier drain ----
        #pragma unroll
        for (int tt = 0; tt < 2; ++tt)
            bcur[tt] = wsWf[(half * 2 + tt) * 64 + lane];
    }

    __syncthreads();   // both waves' strips complete (lgkmcnt(0)) & visible to the pair

    if (gbase < M) {
        // ---- MFMA: full 16-row A from shared strip; B split by half; double-buffered regs ----
        f32x4 acc[2] = {};
        bf16x8 bnxt[2];
        const int* ar  = hp + col * 128;   // A row m = col
        const int  rot = col * 4;          // undo rotation swizzle on read
        int   z0[8], z1[8];                // cached z-words (s0/s1), reused for means (s2/s3)
        float cnt0[8], cnt1[8], rcp0[8], rcp1[8];
        #pragma unroll
        for (int s = 0; s < 6; ++s) {
            if (s < 5) {
                #pragma unroll
                for (int tt = 0; tt < 2; ++tt)
                    bnxt[tt] = wsWf[((s + 1) * 4 + half * 2 + tt) * 64 + lane];
            }
            float av[8];
            if (s == 0 || s == 1) {
                // z-words for bins s*32 + quad*8 + {0..7}; av = count
                const int o0 = (s * 32 + quad * 8 + rot) & 63;
                const int o1 = (s * 32 + quad * 8 + 4 + rot) & 63;
                const i32x4 a0 = *(const i32x4*)(ar + o0);
                const i32x4 a1 = *(const i32x4*)(ar + o1);
                int* zc = (s == 0) ? z0 : z1;
                float* cc = (s == 0) ? cnt0 : cnt1;
                zc[0]=a0.x; zc[1]=a0.y; zc[2]=a0.z; zc[3]=a0.w;
                zc[4]=a1.x; zc[5]=a1.y; zc[6]=a1.z; zc[7]=a1.w;
                #pragma unroll
                for (int j = 0; j < 8; ++j) { cc[j] = (float)(zc[j] >> 24); av[j] = cc[j]; }
            } else if (s == 2 || s == 3) {
                // no ds_read: mean_z from cached z-words; build reciprocals (2^-13 folded)
                const int*   zc = (s == 2) ? z0 : z1;
                const float* cc = (s == 2) ? cnt0 : cnt1;
                float* rp = (s == 2) ? rcp0 : rcp1;
                #pragma unroll
                for (int j = 0; j < 8; ++j) {
                    rp[j] = __builtin_amdgcn_rcpf(cc[j] + 1e-5f) * INV_QS;
                    const float pay = (float)(zc[j] & 0xFFFFFF);            // exact (<2^24)
                    av[j] = (pay - cc[j] * PBIASF) * rp[j];
                }
            } else {
                // r-words at plane offset 64; mean_r with cached count/rcp
                const int o0 = ((s - 4) * 32 + quad * 8 + rot) & 63;
                const int o1 = ((s - 4) * 32 + quad * 8 + 4 + rot) & 63;
                const i32x4 a0 = *(const i32x4*)(ar + 64 + o0);
                const i32x4 a1 = *(const i32x4*)(ar + 64 + o1);
                const int rv[8] = {a0.x, a0.y, a0.z, a0.w, a1.x, a1.y, a1.z, a1.w};
                const float* cc = (s == 4) ? cnt0 : cnt1;
                const float* rp = (s == 4) ? rcp0 : rcp1;
                #pragma unroll
                for (int j = 0; j < 8; ++j)
                    av[j] = ((float)rv[j] - cc[j] * PBIASF) * rp[j];
            }
            bf16x8 af;
            #pragma unroll
            for (int j = 0; j < 8; ++j) af[j] = f2bf(av[j]);
            #pragma unroll
            for (int tt = 0; tt < 2; ++tt)
                acc[tt] = __builtin_amdgcn_mfma_f32_16x16x32_bf16(af, bcur[tt], acc[tt], 0, 0, 0);
            #pragma unroll
            for (int tt = 0; tt < 2; ++tt) bcur[tt] = bnxt[tt];
        }

        // ---- epilogue: +bias, store x, BN partials. C/D: col=lane&15, row=quad*4+i ----
        #pragma unroll
        for (int tt = 0; tt < 2; ++tt) {
            const int t = half * 2 + tt;
            const float bias = bvec[t * 16 + col];
            #pragma unroll
            for (int i = 0; i < 4; ++i) {
                const int row = gbase + quad * 4 + i;
                if (row < M) {
                    const float xv = acc[tt][i] + bias;
                    xout[(size_t)row * 64 + t * 16 + col] = xv;
                    psum[tt] += xv;
                    psq[tt]  += xv * xv;
                }
            }
        }
    }

    // ---- BN partials: quad-reduce; lanes 0..31 carry this wave's 32 channels ----
    #pragma unroll
    for (int tt = 0; tt < 2; ++tt) {
        psum[tt] += __shfl_xor(psum[tt], 16);
        psum[tt] += __shfl_xor(psum[tt], 32);
        psq[tt]  += __shfl_xor(psq[tt], 16);
        psq[tt]  += __shfl_xor(psq[tt], 32);
    }
    // lane<32: quad in {0,1} selects tt; ch = half*32 + quad*16 + col = (2*half+tt)*16 + col
    const float myS = (quad & 1) ? psum[1] : psum[0];
    const float myQ = (quad & 1) ? psq[1]  : psq[0];
    const int gw = blockIdx.x * 4 + wave;
    if (lane < 32) {
        unsigned long long* dst = totals + (gw & (REPS - 1)) * 128 + half * 32 + lane;
        atomicAdd(dst,      (unsigned long long)(long long)(myS * TSC));
        atomicAdd(dst + 64, (unsigned long long)(long long)(myQ * TSC));
    }
}

__global__ __launch_bounds__(256)
void k3_bn_apply(float4* __restrict__ x,
                 const unsigned long long* __restrict__ totals,
                 const float* __restrict__ gamma,
                 const float* __restrict__ beta,
                 float invM, int n4)
{
    __shared__ float sT[128];
    __shared__ float sa[64];
    __shared__ float sc[64];
    const int t = threadIdx.x;
    if (t < 128) {   // sum replicas: deterministic across blocks
        long long s = 0;
        #pragma unroll
        for (int rep = 0; rep < REPS; ++rep) s += (long long)totals[rep * 128 + t];
        sT[t] = (float)s * (invM * INV_TSC);
    }
    __syncthreads();
    if (t < 64) {
        const float mu   = sT[t];
        const float q    = sT[64 + t];
        const float var  = q - mu * mu;
        const float rstd = 1.0f / sqrtf(var + 1e-5f);
        const float a    = gamma[t] * rstd;
        sa[t] = a;
        sc[t] = beta[t] - mu * a;
    }
    __syncthreads();
    const int stride = gridDim.x * 256;
    for (int i = blockIdx.x * 256 + t; i < n4; i += stride) {
        const float4 a = ((const float4*)sa)[i & 15];   // 64 ch = 16 float4
        const float4 c = ((const float4*)sc)[i & 15];
        float4 v = x[i];
        v.x = fmaxf(fmaf(v.x, a.x, c.x), 0.f);
        v.y = fmaxf(fmaf(v.y, a.y, c.y), 0.f);
        v.z = fmaxf(fmaf(v.z, a.z, c.z), 0.f);
        v.w = fmaxf(fmaf(v.w, a.w, c.w), 0.f);
        x[i] = v;
    }
}

extern "C" void kernel_launch(void* const* d_in, const int* in_sizes, int n_in,
                              void* d_out, int out_size, void* d_ws, size_t ws_size,
                              hipStream_t stream) {
    const uint2*  feat2 = (const uint2*)d_in[0];   // [M,64,4] fp32 viewed as uint2 pairs
    const int*    nump  = (const int*)d_in[1];     // [M]
    // d_in[2] = coors (unused)
    const float*  W     = (const float*)d_in[3];   // [64,192]
    const float*  bvec  = (const float*)d_in[4];   // [64]
    const float*  gamma = (const float*)d_in[5];   // [64]
    const float*  beta  = (const float*)d_in[6];   // [64]

    const int M = in_sizes[1];
    float* xout = (float*)d_out;
    short* wsW  = (short*)d_ws;                                   // [24*64*8] bf16 B-fragments
    unsigned long long* totals =
        (unsigned long long*)((char*)d_ws + 24 * 64 * 8 * sizeof(short));  // [REPS*128] u64

    k0_prep<<<16, 256, 0, stream>>>(W, wsW, totals);

    const int nblk = (M + 31) / 32;   // 32 rows/block (2 pairs x 16 rows)
    k1_hist_mfma<<<nblk, 256, 0, stream>>>(feat2, nump, (const bf16x8*)wsW, bvec, xout, totals, M);

    const int n4 = out_size / 4;
    const int nblk3 = (n4 + 256 * 16 - 1) / (256 * 16);
    k3_bn_apply<<<nblk3, 256, 0, stream>>>((float4*)d_out, totals, gamma, beta,
                                           1.0f / (float)M, n4);
}

// Round 2
// 185.016 us; speedup vs baseline: 1.1008x; 1.0440x over previous
//
#include <hip/hip_runtime.h>
#include <hip/hip_bf16.h>
#include <math.h>

// PillarHist: per-row 64-bin hist (count/mean_z/mean_r interleaved) -> Linear(192->64) -> BN(train) -> ReLU
// k0 (16 blocks): build permuted bf16 B-fragments into d_ws + zero BN totals (16 replicas).
// k1 (6250 blocks, 128 threads = ONE wave pair, 16 rows/block):
//     - u64-packed hist: ONE ds_add_u64 per point (z-word = count<<24 | biased z in hi32,
//       biased r in lo32). Row = 66 u64 (528 B pad -> 8-way-max read bank profile, no swizzle).
//     - Each wave loads+hists 8 rows; ONE pair-exact __syncthreads; both waves MFMA the full
//       16-row A split by output half (t in {2h,2h+1}).
//     - MFMA regrouped by bin-group: 4 contiguous ds_read_b128 deliver z+r for 8 bins; then
//       count/mean_z/mean_r substages (planes g,2+g,4+g) run from registers. 2 LDS-read rounds
//       instead of 4; group-scoped liveness fits 64 VGPRs.
//     - LDS 8448 B/block -> 16 blocks/CU (wave-slot cap) = 32 waves/CU theoretical.
// k3: sum replicas -> scale/shift -> apply BN+ReLU in-place (grid-stride).

typedef __attribute__((ext_vector_type(8))) short bf16x8;   // 8 bf16 = 4 VGPRs = 16 B
typedef __attribute__((ext_vector_type(4))) float f32x4;
typedef __attribute__((ext_vector_type(4))) int   i32x4;

#define ZMINF   (-3.0f)
#define INV_BIN 16.0f            // 1/BIN_SIZE (exact pow2)
#define QS      8192.0f          // 2^13 payload scale
#define INV_QS  (1.0f / 8192.0f)
#define PBIASF  65536.0f         // 2^16 payload bias (covers |z|<8; 64*max_payload < 2^24)
#define PBIASI  65536
#define CBIT    16777216         // 2^24 count increment (hi word only)
#define TSC     16777216.0f     // 2^24 fixed-point scale for BN totals
#define INV_TSC (1.0f / 16777216.0f)
#define REPS    16               // BN total replicas
#define RSTRIDE 66               // u64 per row (64 bins + 2 pad -> bank spread)

__device__ __forceinline__ short f2bf(float f) {
    __hip_bfloat16 h = __float2bfloat16(f);   // RNE
    return __builtin_bit_cast(short, h);
}

// ---- k0: grid-stride. Permuted W -> bf16 fragments (frag-major [s*4+t][lane][j]) + zero totals ----
__global__ __launch_bounds__(256)
void k0_prep(const float* __restrict__ W,                  // [64,192]
             short*       __restrict__ wsW,                // [24*64*8] bf16
             unsigned long long* __restrict__ totals)      // [REPS*128]
{
    const int tid    = blockIdx.x * 256 + threadIdx.x;
    const int stride = gridDim.x * 256;
    for (int e = tid; e < 24 * 64 * 8; e += stride) {
        const int j  = e & 7;
        const int ln = (e >> 3) & 63;
        const int st = e >> 9;                       // s*4+t
        const int s  = st >> 2, t = st & 3;
        const int k  = s * 32 + (ln >> 4) * 8 + j;   // planar k
        const int n  = t * 16 + (ln & 15);           // output channel
        const int wc = (k < 64) ? 3 * k
                     : (k < 128) ? 3 * (k - 64) + 1
                                 : 3 * (k - 128) + 2;
        wsW[e] = f2bf(W[n * 192 + wc]);
    }
    for (int e = tid; e < REPS * 128; e += stride) totals[e] = 0ull;
}

__global__ __launch_bounds__(128, 8)
void k1_hist_mfma(const uint2*  __restrict__ feat2,  // feat as uint2; zw of (row,pt) at (row*64+pt)*2+1
                  const int*    __restrict__ nump,   // [M]
                  const bf16x8* __restrict__ wsWf,   // [24*64] B fragments (global, L2-hot)
                  const float*  __restrict__ bvec,   // [64]
                  float*        __restrict__ xout,   // [M,64] pre-BN x (d_out)
                  unsigned long long* __restrict__ totals, // [REPS*128] fixed-point sum | sumsq
                  int M)
{
    __shared__ unsigned long long sH[16 * RSTRIDE];   // 8448 B: 16 rows x (64 bins u64 + pad)

    const int tid  = threadIdx.x;
    const int wave = tid >> 6;          // 0,1 — one pair per block
    const int lane = tid & 63;
    const int col  = lane & 15;
    const int quad = lane >> 4;
    const int half = wave;              // output half: t in {2*half, 2*half+1}

    const int gbase = blockIdx.x * 16;
    float psum[2] = {0.f, 0.f};
    float psq[2]  = {0.f, 0.f};
    bf16x8 bcur[2];

    if (gbase < M) {
        // ---- 8 rows of z/w per wave in ONE load batch (uint2 = 8 B/lane; 16 VGPRs) ----
        uint2 zw[8];
        const int npv = nump[min(gbase + half * 8 + (lane & 7), M - 1)];  // lanes 0..7 hold own rows
        #pragma unroll
        for (int uu = 0; uu < 8; ++uu) {
            const int rc = min(gbase + half * 8 + uu, M - 1);
            zw[uu] = feat2[((size_t)rc * 64 + lane) * 2 + 1];
        }

        // ---- zero OWN 8-row strip (8*66 u64 = 4224 B); overlaps load latency ----
        {
            i32x4* p4 = (i32x4*)&sH[(size_t)half * 8 * RSTRIDE];
            #pragma unroll
            for (int i = 0; i < 5; ++i) {
                const int idx = lane + i * 64;
                if (idx < (8 * RSTRIDE * 2) / 4) p4[idx] = i32x4{0, 0, 0, 0};
            }
        }
        __builtin_amdgcn_wave_barrier();

        // ---- packed hist, own 8 rows: ONE native ds_add_u64 per point ----
        #pragma unroll
        for (int uu = 0; uu < 8; ++uu) {
            const int u = half * 8 + uu;                         // row within block strip
            int np_u = __builtin_amdgcn_readlane(npv, uu);
            np_u = (gbase + u < M) ? np_u : 0;                   // uniform tail guard
            if (lane < np_u) {
                const float z  = __int_as_float((int)zw[uu].x);
                const float rr = __int_as_float((int)zw[uu].y);
                int bi = (int)((z - ZMINF) * INV_BIN);           // trunc, matches astype(int32)
                bi = min(max(bi, 0), 63);
                const unsigned long long add =
                    ((unsigned long long)(unsigned)(CBIT + PBIASI + (int)(z * QS)) << 32)
                    | (unsigned)(PBIASI + (int)(rr * QS));
                atomicAdd(&sH[u * RSTRIDE + bi], add);
            }
        }

        // ---- prefetch plane-0 B-frags (L2-hot) so they land by the barrier drain ----
        bcur[0] = wsWf[(half * 2 + 0) * 64 + lane];
        bcur[1] = wsWf[(half * 2 + 1) * 64 + lane];
    }

    __syncthreads();   // pair-exact: partner's 8 rows complete & visible

    if (gbase < M) {
        // ---- MFMA: A rows = col; bin-group g covers bins g*32+quad*8..+7 (z+r in one read run) ----
        f32x4 acc[2] = {};
        bf16x8 bnxt[2];
        const int* ar = (const int*)sH + col * (RSTRIDE * 2);   // row col, int view
        #pragma unroll
        for (int g = 0; g < 2; ++g) {
            const int o0 = g * 32 + quad * 8;                   // first bin of this lane's slice
            const i32x4* ap = (const i32x4*)(ar + 2 * o0);      // 64 B contiguous: 8 bins (r,z)x4
            const i32x4 a0 = ap[0], a1 = ap[1], a2 = ap[2], a3 = ap[3];
            const int zz[8]  = {a0.y, a0.w, a1.y, a1.w, a2.y, a2.w, a3.y, a3.w};
            const int rrw[8] = {a0.x, a0.z, a1.x, a1.z, a2.x, a2.z, a3.x, a3.z};
            float cnt[8], rcp[8], av[8];
            bf16x8 af;

            // -- substage A: counts (plane g); prefetch plane 2+g --
            bnxt[0] = wsWf[((2 + g) * 4 + half * 2 + 0) * 64 + lane];
            bnxt[1] = wsWf[((2 + g) * 4 + half * 2 + 1) * 64 + lane];
            #pragma unroll
            for (int j = 0; j < 8; ++j) { cnt[j] = (float)(zz[j] >> 24); av[j] = cnt[j]; }
            #pragma unroll
            for (int j = 0; j < 8; ++j) af[j] = f2bf(av[j]);
            acc[0] = __builtin_amdgcn_mfma_f32_16x16x32_bf16(af, bcur[0], acc[0], 0, 0, 0);
            acc[1] = __builtin_amdgcn_mfma_f32_16x16x32_bf16(af, bcur[1], acc[1], 0, 0, 0);
            bcur[0] = bnxt[0]; bcur[1] = bnxt[1];

            // -- substage B: mean_z (plane 2+g); prefetch plane 4+g --
            bnxt[0] = wsWf[((4 + g) * 4 + half * 2 + 0) * 64 + lane];
            bnxt[1] = wsWf[((4 + g) * 4 + half * 2 + 1) * 64 + lane];
            #pragma unroll
            for (int j = 0; j < 8; ++j) {
                rcp[j] = __builtin_amdgcn_rcpf(cnt[j] + 1e-5f) * INV_QS;
                const float pay = (float)(zz[j] & 0xFFFFFF);            // exact (<2^24)
                av[j] = (pay - cnt[j] * PBIASF) * rcp[j];
            }
            #pragma unroll
            for (int j = 0; j < 8; ++j) af[j] = f2bf(av[j]);
            acc[0] = __builtin_amdgcn_mfma_f32_16x16x32_bf16(af, bcur[0], acc[0], 0, 0, 0);
            acc[1] = __builtin_amdgcn_mfma_f32_16x16x32_bf16(af, bcur[1], acc[1], 0, 0, 0);
            bcur[0] = bnxt[0]; bcur[1] = bnxt[1];

            // -- substage C: mean_r (plane 4+g); prefetch plane 1 when g==0 --
            if (g == 0) {
                bnxt[0] = wsWf[(1 * 4 + half * 2 + 0) * 64 + lane];
                bnxt[1] = wsWf[(1 * 4 + half * 2 + 1) * 64 + lane];
            }
            #pragma unroll
            for (int j = 0; j < 8; ++j)
                av[j] = ((float)rrw[j] - cnt[j] * PBIASF) * rcp[j];
            #pragma unroll
            for (int j = 0; j < 8; ++j) af[j] = f2bf(av[j]);
            acc[0] = __builtin_amdgcn_mfma_f32_16x16x32_bf16(af, bcur[0], acc[0], 0, 0, 0);
            acc[1] = __builtin_amdgcn_mfma_f32_16x16x32_bf16(af, bcur[1], acc[1], 0, 0, 0);
            bcur[0] = bnxt[0]; bcur[1] = bnxt[1];
        }

        // ---- epilogue: +bias, store x, BN partials. C/D: col=lane&15, row=quad*4+i ----
        #pragma unroll
        for (int tt = 0; tt < 2; ++tt) {
            const int t = half * 2 + tt;
            const float bias = bvec[t * 16 + col];
            #pragma unroll
            for (int i = 0; i < 4; ++i) {
                const int row = gbase + quad * 4 + i;
                if (row < M) {
                    const float xv = acc[tt][i] + bias;
                    xout[(size_t)row * 64 + t * 16 + col] = xv;
                    psum[tt] += xv;
                    psq[tt]  += xv * xv;
                }
            }
        }
    }

    // ---- BN partials: quad-reduce; lanes 0..31 carry this wave's 32 channels ----
    #pragma unroll
    for (int tt = 0; tt < 2; ++tt) {
        psum[tt] += __shfl_xor(psum[tt], 16);
        psum[tt] += __shfl_xor(psum[tt], 32);
        psq[tt]  += __shfl_xor(psq[tt], 16);
        psq[tt]  += __shfl_xor(psq[tt], 32);
    }
    // lane<32: quad in {0,1} selects tt; ch = half*32 + quad*16 + col = (2*half+tt)*16 + col
    const float myS = (quad & 1) ? psum[1] : psum[0];
    const float myQ = (quad & 1) ? psq[1]  : psq[0];
    const int gw = blockIdx.x * 2 + wave;
    if (lane < 32) {
        unsigned long long* dst = totals + (gw & (REPS - 1)) * 128 + half * 32 + lane;
        atomicAdd(dst,      (unsigned long long)(long long)(myS * TSC));
        atomicAdd(dst + 64, (unsigned long long)(long long)(myQ * TSC));
    }
}

__global__ __launch_bounds__(256)
void k3_bn_apply(float4* __restrict__ x,
                 const unsigned long long* __restrict__ totals,
                 const float* __restrict__ gamma,
                 const float* __restrict__ beta,
                 float invM, int n4)
{
    __shared__ float sT[128];
    __shared__ float sa[64];
    __shared__ float sc[64];
    const int t = threadIdx.x;
    if (t < 128) {   // sum replicas: deterministic across blocks
        long long s = 0;
        #pragma unroll
        for (int rep = 0; rep < REPS; ++rep) s += (long long)totals[rep * 128 + t];
        sT[t] = (float)s * (invM * INV_TSC);
    }
    __syncthreads();
    if (t < 64) {
        const float mu   = sT[t];
        const float q    = sT[64 + t];
        const float var  = q - mu * mu;
        const float rstd = 1.0f / sqrtf(var + 1e-5f);
        const float a    = gamma[t] * rstd;
        sa[t] = a;
        sc[t] = beta[t] - mu * a;
    }
    __syncthreads();
    const int stride = gridDim.x * 256;
    for (int i = blockIdx.x * 256 + t; i < n4; i += stride) {
        const float4 a = ((const float4*)sa)[i & 15];   // 64 ch = 16 float4
        const float4 c = ((const float4*)sc)[i & 15];
        float4 v = x[i];
        v.x = fmaxf(fmaf(v.x, a.x, c.x), 0.f);
        v.y = fmaxf(fmaf(v.y, a.y, c.y), 0.f);
        v.z = fmaxf(fmaf(v.z, a.z, c.z), 0.f);
        v.w = fmaxf(fmaf(v.w, a.w, c.w), 0.f);
        x[i] = v;
    }
}

extern "C" void kernel_launch(void* const* d_in, const int* in_sizes, int n_in,
                              void* d_out, int out_size, void* d_ws, size_t ws_size,
                              hipStream_t stream) {
    const uint2*  feat2 = (const uint2*)d_in[0];   // [M,64,4] fp32 viewed as uint2 pairs
    const int*    nump  = (const int*)d_in[1];     // [M]
    // d_in[2] = coors (unused)
    const float*  W     = (const float*)d_in[3];   // [64,192]
    const float*  bvec  = (const float*)d_in[4];   // [64]
    const float*  gamma = (const float*)d_in[5];   // [64]
    const float*  beta  = (const float*)d_in[6];   // [64]

    const int M = in_sizes[1];
    float* xout = (float*)d_out;
    short* wsW  = (short*)d_ws;                                   // [24*64*8] bf16 B-fragments
    unsigned long long* totals =
        (unsigned long long*)((char*)d_ws + 24 * 64 * 8 * sizeof(short));  // [REPS*128] u64

    k0_prep<<<16, 256, 0, stream>>>(W, wsW, totals);

    const int nblk = (M + 15) / 16;   // 16 rows/block (one wave pair)
    k1_hist_mfma<<<nblk, 128, 0, stream>>>(feat2, nump, (const bf16x8*)wsW, bvec, xout, totals, M);

    const int n4 = out_size / 4;
    const int nblk3 = (n4 + 256 * 16 - 1) / (256 * 16);
    k3_bn_apply<<<nblk3, 256, 0, stream>>>((float4*)d_out, totals, gamma, beta,
                                           1.0f / (float)M, n4);
}